// Round 15
// baseline (181.848 us; speedup 1.0000x reference)
//
#include <hip/hip_runtime.h>

#define DEVFN __device__ __forceinline__

typedef __attribute__((ext_vector_type(8))) short bf16x8;
typedef __attribute__((ext_vector_type(4))) float f32x4;
typedef __attribute__((ext_vector_type(16))) float f32x16;

#define MFMA16(a, b, c) __builtin_amdgcn_mfma_f32_16x16x32_bf16(a, b, c, 0, 0, 0)
#define MFMA32(a, b, c) __builtin_amdgcn_mfma_f32_32x32x16_bf16(a, b, c, 0, 0, 0)

DEVFN unsigned short f2bf(float f) {
  union { float f; unsigned u; } v; v.f = f;
  unsigned r = v.u + 0x7FFFu + ((v.u >> 16) & 1u);
  return (unsigned short)(r >> 16);
}
DEVFN unsigned pack2bf(float a, float b) {
  return (unsigned)f2bf(a) | ((unsigned)f2bf(b) << 16);
}
DEVFN unsigned cvtpk(float lo, float hi) {
  unsigned r;
  asm("v_cvt_pk_bf16_f32 %0, %1, %2" : "=v"(r) : "v"(lo), "v"(hi));
  return r;
}
DEVFN void pl32swap(unsigned& a, unsigned& b) {
  asm("v_permlane32_swap_b32 %0, %1" : "+v"(a), "+v"(b));
}
DEVFN void gll16(const void* g, void* l) {
  __builtin_amdgcn_global_load_lds((__attribute__((address_space(1))) void*)g,
                                   (__attribute__((address_space(3))) void*)l,
                                   16, 0, 0);
}

// ---------------- fused prep: conv_x (blk<8192) | transp (8192..9215) |
// rope (9216..9471). Independent work -> one launch, concurrent execution.
__global__ __launch_bounds__(256) void prep_k(
    const float* __restrict__ x, unsigned short* __restrict__ xb,
    const float* __restrict__ Wq, const float* __restrict__ Wk,
    const float* __restrict__ Wv, const float* __restrict__ Wo,
    unsigned short* __restrict__ Tq, unsigned short* __restrict__ Tk,
    unsigned short* __restrict__ Tv, unsigned short* __restrict__ To,
    float2* __restrict__ rtab) {
  __shared__ unsigned short t[64 * 65];
  const int blk = blockIdx.x;
  const int tid = threadIdx.x;
  if (blk < 8192) {
    int i = (blk * 256 + tid) * 4;
    float4 v = *(const float4*)(x + i);
    uint2 u;
    u.x = pack2bf(v.x, v.y);
    u.y = pack2bf(v.z, v.w);
    *(uint2*)(xb + i) = u;
  } else if (blk < 9216) {
    const int lb = blk - 8192;
    const int z = lb >> 8, by = (lb >> 4) & 15, bx = lb & 15;
    const float* src = (z == 0) ? Wq : (z == 1) ? Wk : (z == 2) ? Wv : Wo;
    unsigned short* dst = (z == 0) ? Tq : (z == 1) ? Tk : (z == 2) ? Tv : To;
    int k0 = bx * 64, n0 = by * 64;
#pragma unroll
    for (int i = 0; i < 16; ++i) {
      int flat = i * 256 + tid;
      int r = flat >> 6, cc = flat & 63;
      t[cc * 65 + r] = f2bf(src[(size_t)(k0 + r) * 1024 + n0 + cc]);
    }
    __syncthreads();
#pragma unroll
    for (int i = 0; i < 16; ++i) {
      int flat = i * 256 + tid;
      int rr = flat >> 6, cc = flat & 63;
      dst[(size_t)(n0 + rr) * 1024 + k0 + cc] = t[rr * 65 + cc];
    }
  } else {
    int idx = (blk - 9216) * 256 + tid;  // 2048*32
    int s = idx >> 5, j = idx & 31;
    float freq = expf(-0.28782313714981824f * (float)j);
    float ang = (float)s * freq;
    rtab[idx] = make_float2(sinf(ang), cosf(ang));
  }
}

// ---------------- fused QKV GEMM: 3x C[8192,1024] = xb @ {Wq,Wk,Wv} -------
// blockIdx.y: 0..7 -> Q (RoPE+scale, row-major), 8..15 -> K (RoPE,
// fragment-linear Kf), 16..23 -> V (fragment-linear Vf).
__global__ __launch_bounds__(256) void gemm_qkv_k(
    const unsigned short* __restrict__ A, const unsigned short* __restrict__ WTq,
    const unsigned short* __restrict__ WTk, const unsigned short* __restrict__ WTv,
    unsigned short* __restrict__ Qb, unsigned short* __restrict__ Kfb,
    unsigned short* __restrict__ Vfb, const float2* __restrict__ rtab) {
  __shared__ unsigned short At[128 * 64];
  __shared__ unsigned short Bt[128 * 64];
  const int tid = threadIdx.x;
  const int w = tid >> 6, lane = tid & 63, g = lane >> 4, c = lane & 15;
  const int wr = w >> 1, wc = w & 1;
  const int which = blockIdx.y >> 3;  // 0=Q 1=K 2=V
  const unsigned short* WT = (which == 0) ? WTq : (which == 1) ? WTk : WTv;
  const int m0 = blockIdx.x * 128, n0 = (blockIdx.y & 7) * 128;

  f32x4 zero = {0.f, 0.f, 0.f, 0.f};
  f32x4 acc[4][4];
#pragma unroll
  for (int i = 0; i < 4; ++i)
#pragma unroll
    for (int j = 0; j < 4; ++j) acc[i][j] = zero;

  for (int k0 = 0; k0 < 1024; k0 += 64) {
#pragma unroll
    for (int p = 0; p < 4; ++p) {
      int i = p * 256 + tid;
      int row = i >> 3, ls = i & 7;
      size_t off = ((size_t)(m0 + row) * 1024 + k0) * 2 + ((ls ^ (row & 7)) << 4);
      gll16((const char*)A + off, (char*)At + p * 4096 + w * 1024);
      size_t offb = ((size_t)(n0 + row) * 1024 + k0) * 2 + ((ls ^ (row & 7)) << 4);
      gll16((const char*)WT + offb, (char*)Bt + p * 4096 + w * 1024);
    }
    __syncthreads();
#pragma unroll
    for (int ks = 0; ks < 2; ++ks) {
      bf16x8 af[4], bfv[4];
#pragma unroll
      for (int am = 0; am < 4; ++am) {
        int row = wr * 64 + am * 16 + c;
        af[am] = *(const bf16x8*)(At + row * 64 + ((((ks << 2) | g) ^ (row & 7)) << 3));
      }
#pragma unroll
      for (int bn = 0; bn < 4; ++bn) {
        int row = wc * 64 + bn * 16 + c;
        bfv[bn] = *(const bf16x8*)(Bt + row * 64 + ((((ks << 2) | g) ^ (row & 7)) << 3));
      }
#pragma unroll
      for (int am = 0; am < 4; ++am)
#pragma unroll
        for (int bn = 0; bn < 4; ++bn)
          acc[am][bn] = MFMA16(af[am], bfv[bn], acc[am][bn]);
    }
    __syncthreads();
  }

  if (which == 0) {
#pragma unroll
    for (int am = 0; am < 4; ++am)
#pragma unroll
      for (int bp = 0; bp < 2; ++bp) {
        int col = n0 + wc * 64 + bp * 16 + c;
        int h = col >> 6, j = col & 63;
#pragma unroll
        for (int r = 0; r < 4; ++r) {
          int row = m0 + wr * 64 + am * 16 + (g << 2) + r;
          int b = row >> 11, s = row & 2047;
          float x1 = acc[am][bp][r], x2 = acc[am][bp + 2][r];
          float2 sc = rtab[s * 32 + j];
          float o1 = (sc.y * x1 - sc.x * x2) * 0.18033688011112042f;
          float o2 = (sc.x * x1 + sc.y * x2) * 0.18033688011112042f;
          size_t base = (((size_t)(b * 16 + h)) * 2048 + s) * 64;
          Qb[base + j] = f2bf(o1);
          Qb[base + 32 + j] = f2bf(o2);
        }
      }
  } else if (which == 1) {
#pragma unroll
    for (int am = 0; am < 4; ++am)
#pragma unroll
      for (int bp = 0; bp < 2; ++bp) {
        int col = n0 + wc * 64 + bp * 16 + c;
        int h = col >> 6, j = col & 63;  // j in [0,32)
        const int kb = j >> 4, hil = (j >> 3) & 1, el = j & 7;
#pragma unroll
        for (int r = 0; r < 4; ++r) {
          int row = m0 + wr * 64 + am * 16 + (g << 2) + r;
          int b = row >> 11, s = row & 2047;
          float x1 = acc[am][bp][r], x2 = acc[am][bp + 2][r];
          float2 sc = rtab[s * 32 + j];
          float o1 = sc.y * x1 - sc.x * x2;
          float o2 = sc.x * x1 + sc.y * x2;
          size_t base = (size_t)(b * 16 + h) * 131072 + (size_t)(s >> 5) * 2048 +
                        (hil * 32 + (s & 31)) * 8 + el;
          Kfb[base + kb * 512] = f2bf(o1);
          Kfb[base + (kb + 2) * 512] = f2bf(o2);
        }
      }
  } else {
#pragma unroll
    for (int am = 0; am < 4; ++am)
#pragma unroll
      for (int bn = 0; bn < 4; ++bn) {
        int col = n0 + wc * 64 + bn * 16 + c;
        int h = col >> 6, d = col & 63;
        int row0 = m0 + wr * 64 + am * 16 + (g << 2);
        int b = row0 >> 11, s0 = row0 & 2047;
        uint2 u;
        u.x = pack2bf(acc[am][bn][0], acc[am][bn][1]);
        u.y = pack2bf(acc[am][bn][2], acc[am][bn][3]);
        size_t off = (size_t)(b * 16 + h) * 131072 + (size_t)(s0 >> 6) * 4096 +
                     ((s0 >> 4) & 3) * 1024 + (d >> 5) * 512 +
                     (((s0 >> 3) & 1) * 32 + (d & 31)) * 8 + (s0 & 7);
        *(uint2*)(Vfb + off) = u;
      }
  }
}

// ---------------- output GEMM: d_out = ctx @ Wo (fp32) ----------------
__global__ __launch_bounds__(256) void gemm_o_k(
    const unsigned short* __restrict__ A, const unsigned short* __restrict__ WT,
    float* __restrict__ outf) {
  __shared__ unsigned short At[128 * 64];
  __shared__ unsigned short Bt[128 * 64];
  const int tid = threadIdx.x;
  const int w = tid >> 6, lane = tid & 63, g = lane >> 4, c = lane & 15;
  const int wr = w >> 1, wc = w & 1;
  const int m0 = blockIdx.x * 128, n0 = blockIdx.y * 128;

  f32x4 zero = {0.f, 0.f, 0.f, 0.f};
  f32x4 acc[4][4];
#pragma unroll
  for (int i = 0; i < 4; ++i)
#pragma unroll
    for (int j = 0; j < 4; ++j) acc[i][j] = zero;

  for (int k0 = 0; k0 < 1024; k0 += 64) {
#pragma unroll
    for (int p = 0; p < 4; ++p) {
      int i = p * 256 + tid;
      int row = i >> 3, ls = i & 7;
      size_t off = ((size_t)(m0 + row) * 1024 + k0) * 2 + ((ls ^ (row & 7)) << 4);
      gll16((const char*)A + off, (char*)At + p * 4096 + w * 1024);
      size_t offb = ((size_t)(n0 + row) * 1024 + k0) * 2 + ((ls ^ (row & 7)) << 4);
      gll16((const char*)WT + offb, (char*)Bt + p * 4096 + w * 1024);
    }
    __syncthreads();
#pragma unroll
    for (int ks = 0; ks < 2; ++ks) {
      bf16x8 af[4], bfv[4];
#pragma unroll
      for (int am = 0; am < 4; ++am) {
        int row = wr * 64 + am * 16 + c;
        af[am] = *(const bf16x8*)(At + row * 64 + ((((ks << 2) | g) ^ (row & 7)) << 3));
      }
#pragma unroll
      for (int bn = 0; bn < 4; ++bn) {
        int row = wc * 64 + bn * 16 + c;
        bfv[bn] = *(const bf16x8*)(Bt + row * 64 + ((((ks << 2) | g) ^ (row & 7)) << 3));
      }
#pragma unroll
      for (int am = 0; am < 4; ++am)
#pragma unroll
        for (int bn = 0; bn < 4; ++bn)
          acc[am][bn] = MFMA16(af[am], bfv[bn], acc[am][bn]);
    }
    __syncthreads();
  }

#pragma unroll
  for (int am = 0; am < 4; ++am)
#pragma unroll
    for (int bn = 0; bn < 4; ++bn)
#pragma unroll
      for (int r = 0; r < 4; ++r)
        outf[(size_t)(m0 + wr * 64 + am * 16 + (g << 2) + r) * 1024 +
             (n0 + wc * 64 + bn * 16 + c)] = acc[am][bn][r];
}

// ---------------- flash attention (causal, fused-pair shared-K) ------------
// Q: [BH][2048][64] bf16 (pre-scaled 0.125*log2e). Kf/Vf fragment-linear.
// Wave owns units P AND 63-P CONCURRENTLY in one st loop (A=P active while
// st<SA): one K/V fragment load per step feeds TWO QK/PV computations
// (load issue + addressing per unit-step halved) and the two independent
// softmax chains give in-order-issue ILP. 512 blocks, 2048 waves, phase-
// aligned from st=0 (FETCH stays compulsory ~33MB; R10/R11 tripwire).
// vmax/psum as depth-6 TREES (was 32-deep serial chains). ~230 VGPR target
// at 2 waves/SIMD (spill tripwire: WRITE_SIZE).
__global__ __launch_bounds__(256, 2) void attn_k(
    const unsigned short* __restrict__ Q, const unsigned short* __restrict__ Kf,
    const unsigned short* __restrict__ Vf, unsigned short* __restrict__ ctx) {
  const int blk = blockIdx.x;               // 512 blocks
  const int xcd = blk & 7, idx = blk >> 3;  // 8 heads/XCD: K/V L2-resident
  const int bh = (xcd << 3) + (idx & 7);
  const int tid = threadIdx.x;
  const int w = tid >> 6, lane = tid & 63;
  const int hi = lane >> 5, c5 = lane & 31;
  const int P = ((idx >> 3) << 2) + w;      // 0..31 (long pairs dispatched first)
  const int SA = (P >> 1) + 1;              // unit A = P       (1..16 steps)
  const int SB = ((63 - P) >> 1) + 1;       // unit B = 63-P    (17..32 steps)
  const int qwA = P * 32, qwB = (63 - P) * 32;

  const unsigned short* Qbh = Q + (size_t)bh * 2048 * 64;
  const unsigned short* Kbh = Kf + (size_t)bh * 131072;
  const unsigned short* Vbh = Vf + (size_t)bh * 131072;
  const int b = bh >> 4, h = bh & 15;

  f32x16 zacc;
#pragma unroll
  for (int i = 0; i < 16; ++i) zacc[i] = 0.f;

  bf16x8 qfA[4], qfB[4];
#pragma unroll
  for (int kb = 0; kb < 4; ++kb) {
    qfA[kb] = *(const bf16x8*)(Qbh + (size_t)(qwA + c5) * 64 + kb * 16 + hi * 8);
    qfB[kb] = *(const bf16x8*)(Qbh + (size_t)(qwB + c5) * 64 + kb * 16 + hi * 8);
  }

  f32x16 oaccA[2], oaccB[2];
  oaccA[0] = zacc; oaccA[1] = zacc; oaccB[0] = zacc; oaccB[1] = zacc;
  float mA = -1e30f, lA = 0.f, mB = -1e30f, lB = 0.f;

  bf16x8 kf[2][4], vf[2][4];

  auto loadK = [&](int st) {
    const unsigned short* kb_ = Kbh + (size_t)st * 4096 + lane * 8;
#pragma unroll
    for (int t = 0; t < 2; ++t)
#pragma unroll
      for (int kb = 0; kb < 4; ++kb)
        kf[t][kb] = *(const bf16x8*)(kb_ + t * 2048 + kb * 512);
  };
  auto loadV = [&](int st) {
    const unsigned short* vb_ = Vbh + (size_t)st * 4096 + lane * 8;
#pragma unroll
    for (int kb = 0; kb < 4; ++kb) {
      vf[0][kb] = *(const bf16x8*)(vb_ + kb * 1024);
      vf[1][kb] = *(const bf16x8*)(vb_ + kb * 1024 + 512);
    }
  };

  auto qk_unit = [&](const bf16x8 (&qf)[4], f32x16 (&sacc)[2]) {
#pragma unroll
    for (int t = 0; t < 2; ++t) {
      sacc[t] = MFMA32(kf[t][0], qf[0], zacc);
#pragma unroll
      for (int kb = 1; kb < 4; ++kb)
        sacc[t] = MFMA32(kf[t][kb], qf[kb], sacc[t]);
    }
  };

  // mask (diag only) + online softmax (tree reductions) + pword conversion
  auto sm_unit = [&](f32x16 (&sacc)[2], float& m_run, float& l_run,
                     f32x16 (&oacc)[2], unsigned (&pword)[4][4], int st,
                     int Su, int qw) {
    if (st == Su - 1) {
      const int q = qw + c5;
#pragma unroll
      for (int t = 0; t < 2; ++t) {
        const int kvb = st * 64 + t * 32 + (hi << 2);
#pragma unroll
        for (int i = 0; i < 16; ++i) {
          int kv = kvb + (i & 3) + ((i >> 2) << 3);
          if (kv > q) sacc[t][i] = -1e30f;
        }
      }
    }
    // vmax: depth-6 tree (was 16-deep serial chain)
    f32x16 mx;
#pragma unroll
    for (int i = 0; i < 16; ++i) mx[i] = fmaxf(sacc[0][i], sacc[1][i]);
    float hx[8];
#pragma unroll
    for (int i = 0; i < 8; ++i) hx[i] = fmaxf(mx[i], mx[i + 8]);
    float q0 = fmaxf(hx[0], hx[4]), q1 = fmaxf(hx[1], hx[5]);
    float q2 = fmaxf(hx[2], hx[6]), q3 = fmaxf(hx[3], hx[7]);
    float vmax = fmaxf(fmaxf(q0, q1), fmaxf(q2, q3));
    vmax = fmaxf(vmax, __shfl_xor(vmax, 32, 64));
    if (!__all(vmax <= m_run + 8.0f)) {  // defer-max (log2 domain, THR=8)
      float m_new = fmaxf(m_run, vmax);
      float alpha = exp2f(m_run - m_new);
      l_run *= alpha;
#pragma unroll
      for (int i = 0; i < 16; ++i) {
        oacc[0][i] *= alpha;
        oacc[1][i] *= alpha;
      }
      m_run = m_new;
    }
#pragma unroll
    for (int t = 0; t < 2; ++t)
#pragma unroll
      for (int i = 0; i < 16; ++i) sacc[t][i] = exp2f(sacc[t][i] - m_run);
    // psum: depth-6 tree (was 32-deep serial chain)
    f32x16 sm;
#pragma unroll
    for (int i = 0; i < 16; ++i) sm[i] = sacc[0][i] + sacc[1][i];
    float gx[8];
#pragma unroll
    for (int i = 0; i < 8; ++i) gx[i] = sm[i] + sm[i + 8];
    float p0 = gx[0] + gx[4], p1 = gx[1] + gx[5];
    float p2 = gx[2] + gx[6], p3 = gx[3] + gx[7];
    float psum = (p0 + p1) + (p2 + p3);
    psum += __shfl_xor(psum, 32, 64);
    l_run += psum;
    // P -> bf16 PV B-fragments: 16 cvt_pk + 8 permlane32_swap
#pragma unroll
    for (int t = 0; t < 2; ++t) {
      unsigned X[4][2];
#pragma unroll
      for (int u2 = 0; u2 < 4; ++u2)
#pragma unroll
        for (int wp = 0; wp < 2; ++wp)
          X[u2][wp] = cvtpk(sacc[t][u2 * 4 + 2 * wp], sacc[t][u2 * 4 + 2 * wp + 1]);
#pragma unroll
      for (int par = 0; par < 2; ++par) {
        const int kb = 2 * t + par;
#pragma unroll
        for (int wp = 0; wp < 2; ++wp) {
          unsigned a = X[2 * par][wp], b2 = X[2 * par + 1][wp];
          pl32swap(a, b2);
          pword[kb][wp] = a;
          pword[kb][wp + 2] = b2;
        }
      }
    }
  };

  auto pv_unit = [&](const unsigned (&pword)[4][4], f32x16 (&oacc)[2]) {
#pragma unroll
    for (int kb = 0; kb < 4; ++kb) {
      union { unsigned u[4]; bf16x8 v; } pw;
#pragma unroll
      for (int k2 = 0; k2 < 4; ++k2) pw.u[k2] = pword[kb][k2];
      oacc[0] = MFMA32(vf[0][kb], pw.v, oacc[0]);
      oacc[1] = MFMA32(vf[1][kb], pw.v, oacc[1]);
    }
  };

  loadK(0);
  for (int st = 0; st < SB; ++st) {
    const bool actA = (st < SA);
    f32x16 saccA[2], saccB[2];
    __builtin_amdgcn_s_setprio(1);
    if (actA) qk_unit(qfA, saccA);
    qk_unit(qfB, saccB);
    __builtin_amdgcn_s_setprio(0);
    if (st + 1 < SB) loadK(st + 1);  // in-flight across softmax+PV
    loadV(st);                        // in-flight across softmax
    unsigned pwA[4][4], pwB[4][4];
    if (actA) sm_unit(saccA, mA, lA, oaccA, pwA, st, SA, qwA);
    sm_unit(saccB, mB, lB, oaccB, pwB, st, SB, qwB);
    __builtin_amdgcn_s_setprio(1);
    if (actA) pv_unit(pwA, oaccA);
    pv_unit(pwB, oaccB);
    __builtin_amdgcn_s_setprio(0);
  }

  // epilogue: both units
  auto epi = [&](const f32x16 (&oacc)[2], float l_run, int qw) {
    const float linv = 1.f / l_run;
    unsigned short* crow = ctx + ((size_t)(b * 2048 + qw + c5)) * 1024 + h * 64;
#pragma unroll
    for (int dt = 0; dt < 2; ++dt)
#pragma unroll
      for (int u = 0; u < 4; ++u) {
        int d0 = dt * 32 + 8 * u + 4 * hi;
        uint2 o;
        o.x = cvtpk(oacc[dt][4 * u] * linv, oacc[dt][4 * u + 1] * linv);
        o.y = cvtpk(oacc[dt][4 * u + 2] * linv, oacc[dt][4 * u + 3] * linv);
        *(uint2*)(crow + d0) = o;
      }
  };
  epi(oaccA, lA, qwA);
  epi(oaccB, lB, qwB);
}

// ---------------- launcher ----------------

extern "C" void kernel_launch(void* const* d_in, const int* in_sizes, int n_in,
                              void* d_out, int out_size, void* d_ws, size_t ws_size,
                              hipStream_t stream) {
  (void)in_sizes; (void)n_in; (void)out_size; (void)ws_size;
  const float* x = (const float*)d_in[0];
  const float* Wq = (const float*)d_in[1];
  const float* Wk = (const float*)d_in[2];
  const float* Wv = (const float*)d_in[3];
  const float* Wo = (const float*)d_in[4];
  char* ws = (char*)d_ws;
  const size_t MiB = 1024 * 1024;
  unsigned short* xb  = (unsigned short*)(ws);             // 16 MiB
  unsigned short* WTq = (unsigned short*)(ws + 16 * MiB);  // 2 MiB each
  unsigned short* WTk = (unsigned short*)(ws + 18 * MiB);
  unsigned short* WTv = (unsigned short*)(ws + 20 * MiB);
  unsigned short* WTo = (unsigned short*)(ws + 22 * MiB);
  unsigned short* Qb  = (unsigned short*)(ws + 24 * MiB);  // 16 MiB each
  unsigned short* Kfb = (unsigned short*)(ws + 40 * MiB);
  unsigned short* Vfb = (unsigned short*)(ws + 56 * MiB);
  unsigned short* ctx = (unsigned short*)(ws + 72 * MiB);
  float2* rtab = (float2*)(ws + 88 * MiB);                 // 512 KiB

  prep_k<<<9472, 256, 0, stream>>>(x, xb, Wq, Wk, Wv, Wo, WTq, WTk, WTv, WTo, rtab);
  gemm_qkv_k<<<dim3(64, 24), 256, 0, stream>>>(xb, WTq, WTk, WTv, Qb, Kfb, Vfb, rtab);
  attn_k<<<512, 256, 0, stream>>>(Qb, Kfb, Vfb, ctx);
  gemm_o_k<<<dim3(64, 8), 256, 0, stream>>>(ctx, WTo, (float*)d_out);
}

// Round 16
// 175.738 us; speedup vs baseline: 1.0348x; 1.0348x over previous
//
#include <hip/hip_runtime.h>

#define DEVFN __device__ __forceinline__

typedef __attribute__((ext_vector_type(8))) short bf16x8;
typedef __attribute__((ext_vector_type(4))) float f32x4;
typedef __attribute__((ext_vector_type(16))) float f32x16;

#define MFMA16(a, b, c) __builtin_amdgcn_mfma_f32_16x16x32_bf16(a, b, c, 0, 0, 0)
#define MFMA32(a, b, c) __builtin_amdgcn_mfma_f32_32x32x16_bf16(a, b, c, 0, 0, 0)

DEVFN unsigned short f2bf(float f) {
  union { float f; unsigned u; } v; v.f = f;
  unsigned r = v.u + 0x7FFFu + ((v.u >> 16) & 1u);
  return (unsigned short)(r >> 16);
}
DEVFN unsigned pack2bf(float a, float b) {
  return (unsigned)f2bf(a) | ((unsigned)f2bf(b) << 16);
}
DEVFN unsigned cvtpk(float lo, float hi) {
  unsigned r;
  asm("v_cvt_pk_bf16_f32 %0, %1, %2" : "=v"(r) : "v"(lo), "v"(hi));
  return r;
}
DEVFN void pl32swap(unsigned& a, unsigned& b) {
  asm("v_permlane32_swap_b32 %0, %1" : "+v"(a), "+v"(b));
}
// cross-half reduce via permlane32_swap. R6's NaN root cause: b=a aliased to
// ONE physical register -> self-swap lost the own-half value. Explicit v_mov
// guarantees distinct registers; then between a and b every lane sees both
// x[i] and x[i^32] under either half-exchange convention.
DEVFN float halfmax(float x) {
  unsigned a = __float_as_uint(x), b;
  asm("v_mov_b32 %0, %1" : "=v"(b) : "v"(a));
  pl32swap(a, b);
  return fmaxf(__uint_as_float(a), __uint_as_float(b));
}
DEVFN float halfsum(float x) {
  unsigned a = __float_as_uint(x), b;
  asm("v_mov_b32 %0, %1" : "=v"(b) : "v"(a));
  pl32swap(a, b);
  return __uint_as_float(a) + __uint_as_float(b);
}
DEVFN void gll16(const void* g, void* l) {
  __builtin_amdgcn_global_load_lds((__attribute__((address_space(1))) void*)g,
                                   (__attribute__((address_space(3))) void*)l,
                                   16, 0, 0);
}

// ---------------- fused prep: conv_x (blk<8192) | transp (8192..9215) |
// rope (9216..9471) ----------------
__global__ __launch_bounds__(256) void prep_k(
    const float* __restrict__ x, unsigned short* __restrict__ xb,
    const float* __restrict__ Wq, const float* __restrict__ Wk,
    const float* __restrict__ Wv, const float* __restrict__ Wo,
    unsigned short* __restrict__ Tq, unsigned short* __restrict__ Tk,
    unsigned short* __restrict__ Tv, unsigned short* __restrict__ To,
    float2* __restrict__ rtab) {
  __shared__ unsigned short t[64 * 65];
  const int blk = blockIdx.x;
  const int tid = threadIdx.x;
  if (blk < 8192) {
    int i = (blk * 256 + tid) * 4;
    float4 v = *(const float4*)(x + i);
    uint2 u;
    u.x = pack2bf(v.x, v.y);
    u.y = pack2bf(v.z, v.w);
    *(uint2*)(xb + i) = u;
  } else if (blk < 9216) {
    const int lb = blk - 8192;
    const int z = lb >> 8, by = (lb >> 4) & 15, bx = lb & 15;
    const float* src = (z == 0) ? Wq : (z == 1) ? Wk : (z == 2) ? Wv : Wo;
    unsigned short* dst = (z == 0) ? Tq : (z == 1) ? Tk : (z == 2) ? Tv : To;
    int k0 = bx * 64, n0 = by * 64;
#pragma unroll
    for (int i = 0; i < 16; ++i) {
      int flat = i * 256 + tid;
      int r = flat >> 6, cc = flat & 63;
      t[cc * 65 + r] = f2bf(src[(size_t)(k0 + r) * 1024 + n0 + cc]);
    }
    __syncthreads();
#pragma unroll
    for (int i = 0; i < 16; ++i) {
      int flat = i * 256 + tid;
      int rr = flat >> 6, cc = flat & 63;
      dst[(size_t)(n0 + rr) * 1024 + k0 + cc] = t[rr * 65 + cc];
    }
  } else {
    int idx = (blk - 9216) * 256 + tid;  // 2048*32
    int s = idx >> 5, j = idx & 31;
    float freq = expf(-0.28782313714981824f * (float)j);
    float ang = (float)s * freq;
    rtab[idx] = make_float2(sinf(ang), cosf(ang));
  }
}

// ---------------- fused QKV GEMM: 3x C[8192,1024] = xb @ {Wq,Wk,Wv} -------
// blockIdx.y: 0..7 -> Q (RoPE+scale, row-major), 8..15 -> K (RoPE,
// fragment-linear Kf), 16..23 -> V (fragment-linear Vf).
__global__ __launch_bounds__(256) void gemm_qkv_k(
    const unsigned short* __restrict__ A, const unsigned short* __restrict__ WTq,
    const unsigned short* __restrict__ WTk, const unsigned short* __restrict__ WTv,
    unsigned short* __restrict__ Qb, unsigned short* __restrict__ Kfb,
    unsigned short* __restrict__ Vfb, const float2* __restrict__ rtab) {
  __shared__ unsigned short At[128 * 64];
  __shared__ unsigned short Bt[128 * 64];
  const int tid = threadIdx.x;
  const int w = tid >> 6, lane = tid & 63, g = lane >> 4, c = lane & 15;
  const int wr = w >> 1, wc = w & 1;
  const int which = blockIdx.y >> 3;  // 0=Q 1=K 2=V
  const unsigned short* WT = (which == 0) ? WTq : (which == 1) ? WTk : WTv;
  const int m0 = blockIdx.x * 128, n0 = (blockIdx.y & 7) * 128;

  f32x4 zero = {0.f, 0.f, 0.f, 0.f};
  f32x4 acc[4][4];
#pragma unroll
  for (int i = 0; i < 4; ++i)
#pragma unroll
    for (int j = 0; j < 4; ++j) acc[i][j] = zero;

  for (int k0 = 0; k0 < 1024; k0 += 64) {
#pragma unroll
    for (int p = 0; p < 4; ++p) {
      int i = p * 256 + tid;
      int row = i >> 3, ls = i & 7;
      size_t off = ((size_t)(m0 + row) * 1024 + k0) * 2 + ((ls ^ (row & 7)) << 4);
      gll16((const char*)A + off, (char*)At + p * 4096 + w * 1024);
      size_t offb = ((size_t)(n0 + row) * 1024 + k0) * 2 + ((ls ^ (row & 7)) << 4);
      gll16((const char*)WT + offb, (char*)Bt + p * 4096 + w * 1024);
    }
    __syncthreads();
#pragma unroll
    for (int ks = 0; ks < 2; ++ks) {
      bf16x8 af[4], bfv[4];
#pragma unroll
      for (int am = 0; am < 4; ++am) {
        int row = wr * 64 + am * 16 + c;
        af[am] = *(const bf16x8*)(At + row * 64 + ((((ks << 2) | g) ^ (row & 7)) << 3));
      }
#pragma unroll
      for (int bn = 0; bn < 4; ++bn) {
        int row = wc * 64 + bn * 16 + c;
        bfv[bn] = *(const bf16x8*)(Bt + row * 64 + ((((ks << 2) | g) ^ (row & 7)) << 3));
      }
#pragma unroll
      for (int am = 0; am < 4; ++am)
#pragma unroll
        for (int bn = 0; bn < 4; ++bn)
          acc[am][bn] = MFMA16(af[am], bfv[bn], acc[am][bn]);
    }
    __syncthreads();
  }

  if (which == 0) {
#pragma unroll
    for (int am = 0; am < 4; ++am)
#pragma unroll
      for (int bp = 0; bp < 2; ++bp) {
        int col = n0 + wc * 64 + bp * 16 + c;
        int h = col >> 6, j = col & 63;
#pragma unroll
        for (int r = 0; r < 4; ++r) {
          int row = m0 + wr * 64 + am * 16 + (g << 2) + r;
          int b = row >> 11, s = row & 2047;
          float x1 = acc[am][bp][r], x2 = acc[am][bp + 2][r];
          float2 sc = rtab[s * 32 + j];
          float o1 = (sc.y * x1 - sc.x * x2) * 0.18033688011112042f;
          float o2 = (sc.x * x1 + sc.y * x2) * 0.18033688011112042f;
          size_t base = (((size_t)(b * 16 + h)) * 2048 + s) * 64;
          Qb[base + j] = f2bf(o1);
          Qb[base + 32 + j] = f2bf(o2);
        }
      }
  } else if (which == 1) {
#pragma unroll
    for (int am = 0; am < 4; ++am)
#pragma unroll
      for (int bp = 0; bp < 2; ++bp) {
        int col = n0 + wc * 64 + bp * 16 + c;
        int h = col >> 6, j = col & 63;  // j in [0,32)
        const int kb = j >> 4, hil = (j >> 3) & 1, el = j & 7;
#pragma unroll
        for (int r = 0; r < 4; ++r) {
          int row = m0 + wr * 64 + am * 16 + (g << 2) + r;
          int b = row >> 11, s = row & 2047;
          float x1 = acc[am][bp][r], x2 = acc[am][bp + 2][r];
          float2 sc = rtab[s * 32 + j];
          float o1 = sc.y * x1 - sc.x * x2;
          float o2 = sc.x * x1 + sc.y * x2;
          size_t base = (size_t)(b * 16 + h) * 131072 + (size_t)(s >> 5) * 2048 +
                        (hil * 32 + (s & 31)) * 8 + el;
          Kfb[base + kb * 512] = f2bf(o1);
          Kfb[base + (kb + 2) * 512] = f2bf(o2);
        }
      }
  } else {
#pragma unroll
    for (int am = 0; am < 4; ++am)
#pragma unroll
      for (int bn = 0; bn < 4; ++bn) {
        int col = n0 + wc * 64 + bn * 16 + c;
        int h = col >> 6, d = col & 63;
        int row0 = m0 + wr * 64 + am * 16 + (g << 2);
        int b = row0 >> 11, s0 = row0 & 2047;
        uint2 u;
        u.x = pack2bf(acc[am][bn][0], acc[am][bn][1]);
        u.y = pack2bf(acc[am][bn][2], acc[am][bn][3]);
        size_t off = (size_t)(b * 16 + h) * 131072 + (size_t)(s0 >> 6) * 4096 +
                     ((s0 >> 4) & 3) * 1024 + (d >> 5) * 512 +
                     (((s0 >> 3) & 1) * 32 + (d & 31)) * 8 + (s0 & 7);
        *(uint2*)(Vfb + off) = u;
      }
  }
}

// ---------------- output GEMM: d_out = ctx @ Wo (fp32) ----------------
__global__ __launch_bounds__(256) void gemm_o_k(
    const unsigned short* __restrict__ A, const unsigned short* __restrict__ WT,
    float* __restrict__ outf) {
  __shared__ unsigned short At[128 * 64];
  __shared__ unsigned short Bt[128 * 64];
  const int tid = threadIdx.x;
  const int w = tid >> 6, lane = tid & 63, g = lane >> 4, c = lane & 15;
  const int wr = w >> 1, wc = w & 1;
  const int m0 = blockIdx.x * 128, n0 = blockIdx.y * 128;

  f32x4 zero = {0.f, 0.f, 0.f, 0.f};
  f32x4 acc[4][4];
#pragma unroll
  for (int i = 0; i < 4; ++i)
#pragma unroll
    for (int j = 0; j < 4; ++j) acc[i][j] = zero;

  for (int k0 = 0; k0 < 1024; k0 += 64) {
#pragma unroll
    for (int p = 0; p < 4; ++p) {
      int i = p * 256 + tid;
      int row = i >> 3, ls = i & 7;
      size_t off = ((size_t)(m0 + row) * 1024 + k0) * 2 + ((ls ^ (row & 7)) << 4);
      gll16((const char*)A + off, (char*)At + p * 4096 + w * 1024);
      size_t offb = ((size_t)(n0 + row) * 1024 + k0) * 2 + ((ls ^ (row & 7)) << 4);
      gll16((const char*)WT + offb, (char*)Bt + p * 4096 + w * 1024);
    }
    __syncthreads();
#pragma unroll
    for (int ks = 0; ks < 2; ++ks) {
      bf16x8 af[4], bfv[4];
#pragma unroll
      for (int am = 0; am < 4; ++am) {
        int row = wr * 64 + am * 16 + c;
        af[am] = *(const bf16x8*)(At + row * 64 + ((((ks << 2) | g) ^ (row & 7)) << 3));
      }
#pragma unroll
      for (int bn = 0; bn < 4; ++bn) {
        int row = wc * 64 + bn * 16 + c;
        bfv[bn] = *(const bf16x8*)(Bt + row * 64 + ((((ks << 2) | g) ^ (row & 7)) << 3));
      }
#pragma unroll
      for (int am = 0; am < 4; ++am)
#pragma unroll
        for (int bn = 0; bn < 4; ++bn)
          acc[am][bn] = MFMA16(af[am], bfv[bn], acc[am][bn]);
    }
    __syncthreads();
  }

#pragma unroll
  for (int am = 0; am < 4; ++am)
#pragma unroll
    for (int bn = 0; bn < 4; ++bn)
#pragma unroll
      for (int r = 0; r < 4; ++r)
        outf[(size_t)(m0 + wr * 64 + am * 16 + (g << 2) + r) * 1024 +
             (n0 + wc * 64 + bn * 16 + c)] = acc[am][bn][r];
}

// ---------------- flash attention (causal, barrier-free, frag-linear) ------
// R12 body verbatim (validated 80.3us): 512 blocks, wave = 32 q-rows,
// autonomous, units P then 63-P (33 steps, zero tail), phase-aligned from
// st=0, K/V ping-pong double-buffered via manual 2-unroll (static buffer
// indices, rule #20). ONLY change: cross-half reduces via permlane32_swap
// with forced-distinct registers (replaces 2 ds_bpermute LDS round-trips in
// the serial softmax chain).
__global__ __launch_bounds__(256, 2) void attn_k(
    const unsigned short* __restrict__ Q, const unsigned short* __restrict__ Kf,
    const unsigned short* __restrict__ Vf, unsigned short* __restrict__ ctx) {
  const int blk = blockIdx.x;               // 512 blocks
  const int xcd = blk & 7, idx = blk >> 3;  // 8 heads/XCD: K/V L2-resident
  const int bh = (xcd << 3) + (idx & 7);
  const int pbase = (idx >> 3) << 2;
  const int tid = threadIdx.x;
  const int w = tid >> 6, lane = tid & 63;
  const int hi = lane >> 5, c5 = lane & 31;
  const int P = pbase + w;  // 0..31; wave does units P and 63-P

  const unsigned short* Qbh = Q + (size_t)bh * 2048 * 64;
  const unsigned short* Kbh = Kf + (size_t)bh * 131072;
  const unsigned short* Vbh = Vf + (size_t)bh * 131072;
  const int b = bh >> 4, h = bh & 15;

  f32x16 zacc;
#pragma unroll
  for (int i = 0; i < 16; ++i) zacc[i] = 0.f;

  auto pass = [&](int U) {
    const int qw = U * 32;
    const int S = (U >> 1) + 1;  // steps 0..S-1; diagonal at S-1

    bf16x8 qf[4];
#pragma unroll
    for (int kb = 0; kb < 4; ++kb)
      qf[kb] = *(const bf16x8*)(Qbh + (size_t)(qw + c5) * 64 + kb * 16 + hi * 8);

    f32x16 oacc[2];
    oacc[0] = zacc; oacc[1] = zacc;
    float m_run = -1e30f, l_run = 0.f;

    bf16x8 kfA[2][4], vfA[2][4], kfB[2][4], vfB[2][4];

    auto loadK = [&](int st, bf16x8 (&dst)[2][4]) {
      const unsigned short* kb_ = Kbh + (size_t)st * 4096 + lane * 8;
#pragma unroll
      for (int t = 0; t < 2; ++t)
#pragma unroll
        for (int kb = 0; kb < 4; ++kb)
          dst[t][kb] = *(const bf16x8*)(kb_ + t * 2048 + kb * 512);
    };
    auto loadV = [&](int st, bf16x8 (&dst)[2][4]) {
      const unsigned short* vb_ = Vbh + (size_t)st * 4096 + lane * 8;
#pragma unroll
      for (int kb = 0; kb < 4; ++kb) {
        dst[0][kb] = *(const bf16x8*)(vb_ + kb * 1024);
        dst[1][kb] = *(const bf16x8*)(vb_ + kb * 1024 + 512);
      }
    };

    auto step = [&](int st, bf16x8 (&kfC)[2][4], bf16x8 (&vfC)[2][4],
                    bf16x8 (&kfN)[2][4], bf16x8 (&vfN)[2][4]) {
      // ---- QK^T ----
      f32x16 sacc[2];
      __builtin_amdgcn_s_setprio(1);
#pragma unroll
      for (int t = 0; t < 2; ++t) {
        sacc[t] = MFMA32(kfC[t][0], qf[0], zacc);
#pragma unroll
        for (int kb = 1; kb < 4; ++kb)
          sacc[t] = MFMA32(kfC[t][kb], qf[kb], sacc[t]);
      }
      __builtin_amdgcn_s_setprio(0);

      // ---- prefetch next step's K and V (full iteration of cover) ----
      if (st + 1 < S) {
        loadK(st + 1, kfN);
        loadV(st + 1, vfN);
      }

      // ---- causal mask (diagonal step only) ----
      if (st == S - 1) {
        const int q = qw + c5;
#pragma unroll
        for (int t = 0; t < 2; ++t) {
          const int kvb = st * 64 + t * 32 + (hi << 2);
#pragma unroll
          for (int i = 0; i < 16; ++i) {
            int kv = kvb + (i & 3) + ((i >> 2) << 3);
            if (kv > q) sacc[t][i] = -1e30f;
          }
        }
      }

      // ---- online softmax (q lane-local; permlane cross-half reduce) ----
      float vmax = fmaxf(sacc[0][0], sacc[0][1]);
#pragma unroll
      for (int t = 0; t < 2; ++t)
#pragma unroll
        for (int i = (t == 0 ? 2 : 0); i < 16; i += 2)
          vmax = fmaxf(vmax, fmaxf(sacc[t][i], sacc[t][i + 1]));  // v_max3
      vmax = halfmax(vmax);
      if (!__all(vmax <= m_run + 8.0f)) {  // defer-max (log2 domain, THR=8)
        float m_new = fmaxf(m_run, vmax);
        float alpha = exp2f(m_run - m_new);
        l_run *= alpha;
#pragma unroll
        for (int i = 0; i < 16; ++i) {
          oacc[0][i] *= alpha;
          oacc[1][i] *= alpha;
        }
        m_run = m_new;
      }
      float psum = 0.f;
#pragma unroll
      for (int t = 0; t < 2; ++t)
#pragma unroll
        for (int i = 0; i < 16; ++i) {
          float pv = exp2f(sacc[t][i] - m_run);
          sacc[t][i] = pv;
          psum += pv;
        }
      l_run += halfsum(psum);

      // ---- P -> bf16 PV B-fragments: 16 cvt_pk + 8 permlane32_swap ----
      unsigned pword[4][4];
#pragma unroll
      for (int t = 0; t < 2; ++t) {
        unsigned X[4][2];
#pragma unroll
        for (int u2 = 0; u2 < 4; ++u2)
#pragma unroll
          for (int wp = 0; wp < 2; ++wp)
            X[u2][wp] = cvtpk(sacc[t][u2 * 4 + 2 * wp], sacc[t][u2 * 4 + 2 * wp + 1]);
#pragma unroll
        for (int par = 0; par < 2; ++par) {
          const int kb = 2 * t + par;
#pragma unroll
          for (int wp = 0; wp < 2; ++wp) {
            unsigned a = X[2 * par][wp], b2 = X[2 * par + 1][wp];
            pl32swap(a, b2);
            pword[kb][wp] = a;
            pword[kb][wp + 2] = b2;
          }
        }
      }

      // ---- PV ----
      __builtin_amdgcn_s_setprio(1);
#pragma unroll
      for (int kb = 0; kb < 4; ++kb) {
        union { unsigned u[4]; bf16x8 v; } pw;
#pragma unroll
        for (int k2 = 0; k2 < 4; ++k2) pw.u[k2] = pword[kb][k2];
        oacc[0] = MFMA32(vfC[0][kb], pw.v, oacc[0]);
        oacc[1] = MFMA32(vfC[1][kb], pw.v, oacc[1]);
      }
      __builtin_amdgcn_s_setprio(0);
    };

    loadK(0, kfA);
    loadV(0, vfA);
    for (int st = 0; st < S; st += 2) {
      step(st, kfA, vfA, kfB, vfB);
      if (st + 1 < S) step(st + 1, kfB, vfB, kfA, vfA);
    }

    // ---- epilogue ----
    const float linv = 1.f / l_run;
    unsigned short* crow = ctx + ((size_t)(b * 2048 + qw + c5)) * 1024 + h * 64;
#pragma unroll
    for (int dt = 0; dt < 2; ++dt)
#pragma unroll
      for (int u = 0; u < 4; ++u) {
        int d0 = dt * 32 + 8 * u + 4 * hi;
        uint2 o;
        o.x = cvtpk(oacc[dt][4 * u] * linv, oacc[dt][4 * u + 1] * linv);
        o.y = cvtpk(oacc[dt][4 * u + 2] * linv, oacc[dt][4 * u + 3] * linv);
        *(uint2*)(crow + d0) = o;
      }
  };

  pass(P);
  pass(63 - P);
}

// ---------------- launcher ----------------

extern "C" void kernel_launch(void* const* d_in, const int* in_sizes, int n_in,
                              void* d_out, int out_size, void* d_ws, size_t ws_size,
                              hipStream_t stream) {
  (void)in_sizes; (void)n_in; (void)out_size; (void)ws_size;
  const float* x = (const float*)d_in[0];
  const float* Wq = (const float*)d_in[1];
  const float* Wk = (const float*)d_in[2];
  const float* Wv = (const float*)d_in[3];
  const float* Wo = (const float*)d_in[4];
  char* ws = (char*)d_ws;
  const size_t MiB = 1024 * 1024;
  unsigned short* xb  = (unsigned short*)(ws);             // 16 MiB
  unsigned short* WTq = (unsigned short*)(ws + 16 * MiB);  // 2 MiB each
  unsigned short* WTk = (unsigned short*)(ws + 18 * MiB);
  unsigned short* WTv = (unsigned short*)(ws + 20 * MiB);
  unsigned short* WTo = (unsigned short*)(ws + 22 * MiB);
  unsigned short* Qb  = (unsigned short*)(ws + 24 * MiB);  // 16 MiB each
  unsigned short* Kfb = (unsigned short*)(ws + 40 * MiB);
  unsigned short* Vfb = (unsigned short*)(ws + 56 * MiB);
  unsigned short* ctx = (unsigned short*)(ws + 72 * MiB);
  float2* rtab = (float2*)(ws + 88 * MiB);                 // 512 KiB

  prep_k<<<9472, 256, 0, stream>>>(x, xb, Wq, Wk, Wv, Wo, WTq, WTk, WTv, WTo, rtab);
  gemm_qkv_k<<<dim3(64, 24), 256, 0, stream>>>(xb, WTq, WTk, WTv, Qb, Kfb, Vfb, rtab);
  attn_k<<<512, 256, 0, stream>>>(Qb, Kfb, Vfb, ctx);
  gemm_o_k<<<dim3(64, 8), 256, 0, stream>>>(ctx, WTo, (float*)d_out);
}